// Round 3
// baseline (270.241 us; speedup 1.0000x reference)
//
#include <hip/hip_runtime.h>
#include <hip/hip_bf16.h>

// Problem constants: S=128, D=512, H=8, W=64, NUM=16, SCALE=sqrt(8)
// All inputs and outputs are fp32 (reference dtypes). fp32 compute throughout.
#define INV_SCALE 0.35355339059327373f

// ---------------------------------------------------------------------------
// Fused 4-matrix projection GEMM. y[p] = x[p] @ W[p]^T + b[p]  (torch Linear)
// x: (128,512) fp32; W: (512,512) fp32 row-major [d][k]; y fp32.
// Block = 256 threads handles 2 s-rows x all 512 d (thread: d=t and d=t+256).
// Grid = 4 proj * 64 s-groups = 256 blocks.
// ---------------------------------------------------------------------------
struct Proj4Args {
  const float* x[4];
  const float* w[4];
  const float* b[4];
  float* y[4];
};

__global__ __launch_bounds__(256) void proj4_kernel(Proj4Args A) {
  const int blk = blockIdx.x;
  const int p = blk >> 6;
  const int s0 = (blk & 63) * 2;
  const int t = threadIdx.x;
  __shared__ float xL[2][512];
  {
    const float2* xr = (const float2*)A.x[p];
    float2 f0 = xr[s0 * 256 + t];
    float2 f1 = xr[(s0 + 1) * 256 + t];
    xL[0][2 * t] = f0.x; xL[0][2 * t + 1] = f0.y;
    xL[1][2 * t] = f1.x; xL[1][2 * t + 1] = f1.y;
  }
  __syncthreads();
  const float b0 = A.b[p][t];
  const float b1 = A.b[p][t + 256];
  float a00 = b0, a01 = b1, a10 = b0, a11 = b1;  // [s-sub][d-sub]
  const float* Wp = A.w[p];
  const float4* wr0 = (const float4*)(Wp + t * 512);          // row d = t
  const float4* wr1 = (const float4*)(Wp + (t + 256) * 512);  // row d = t+256
#pragma unroll 8
  for (int k4 = 0; k4 < 128; ++k4) {
    float4 wa = wr0[k4];
    float4 wb = wr1[k4];
    float wv[4] = {wa.x, wa.y, wa.z, wa.w};
    float vv[4] = {wb.x, wb.y, wb.z, wb.w};
    const float* xp0 = &xL[0][k4 * 4];
    const float* xp1 = &xL[1][k4 * 4];
#pragma unroll
    for (int x = 0; x < 4; ++x) {
      float xa = xp0[x], xb = xp1[x];
      a00 = fmaf(wv[x], xa, a00);
      a01 = fmaf(vv[x], xa, a01);
      a10 = fmaf(wv[x], xb, a10);
      a11 = fmaf(vv[x], xb, a11);
    }
  }
  float* yp = A.y[p];
  yp[s0 * 512 + t] = a00;
  yp[s0 * 512 + t + 256] = a01;
  yp[(s0 + 1) * 512 + t] = a10;
  yp[(s0 + 1) * 512 + t + 256] = a11;
}

// ---------------------------------------------------------------------------
// Row-sum factorization + v_res/q_res/a_res/k_res (flat out elems 0..262143).
//   Sum_{j,l} att1[s,i,j,l] = (1/SCALE) sum_c tv[s,i,c]*Sq[s,c]*Sk[s,c], etc.
//   with S*[s,c] = sum over the contiguous 64-chunk c of the projected row.
//   v_res flat [i,s,c] = i*1024+s*8+c; k_res flat [s, w*8+h] at offset 196608.
// Block per s (128 blocks); waves: 0->v_res, 1->q_res, 2->a_res, 3->k_res.
// ---------------------------------------------------------------------------
__global__ __launch_bounds__(256) void post_kernel(
    const float* __restrict__ vp, const float* __restrict__ qp,
    const float* __restrict__ kp, const float* __restrict__ vo,
    const float* __restrict__ qo, const float* __restrict__ ao,
    const float* __restrict__ ko, float* __restrict__ out) {
  const int s = blockIdx.x;
  const int t = threadIdx.x;
  const int wid = t >> 6;
  const int ln = t & 63;
  __shared__ float Ssum[3][8];  // [v,q,k][c]
  const float* srcs[3] = {vp, qp, kp};
#pragma unroll
  for (int tt = 0; tt < 3; ++tt) {
    const float* r = srcs[tt] + s * 512;
    float a = r[wid * 64 + ln];          // chunk c = wid
    float b = r[256 + wid * 64 + ln];    // chunk c = wid+4
#pragma unroll
    for (int o = 32; o; o >>= 1) {
      a += __shfl_xor(a, o);
      b += __shfl_xor(b, o);
    }
    if (ln == 0) { Ssum[tt][wid] = a; Ssum[tt][wid + 4] = b; }
  }
  __syncthreads();
  if (wid == 3) {
    // k_res[s, w*8+h] = ko[s, h*64+w], w=ln
    float tmp[8];
#pragma unroll
    for (int h = 0; h < 8; ++h)
      tmp[h] = ko[s * 512 + h * 64 + ln];
    float4* pp = reinterpret_cast<float4*>(out + 196608 + (s * 64 + ln) * 8);
    pp[0] = make_float4(tmp[0], tmp[1], tmp[2], tmp[3]);
    pp[1] = make_float4(tmp[4], tmp[5], tmp[6], tmp[7]);
  } else {
    // wave0 (v_res): tv=vp, factors Sq*Sk; wave1 (q_res): tq=qp, Sv*Sk;
    // wave2 (a_res): tk=kp, Sv*Sq.
    const float* base = (wid == 0) ? vp : (wid == 1) ? qp : kp;
    const float* obase = (wid == 0) ? vo : (wid == 1) ? qo : ao;
    const int c0 = (wid == 0) ? 1 : 0;
    const int c1 = (wid == 2) ? 1 : 2;
    float A1 = 0.f;
#pragma unroll
    for (int c = 0; c < 8; ++c)
      A1 += base[s * 512 + c * 64 + ln] * (Ssum[c0][c] * Ssum[c1][c]);
    A1 *= INV_SCALE;
    float tmp[8];
#pragma unroll
    for (int c = 0; c < 8; ++c)
      tmp[c] = obase[s * 512 + c * 64 + ln] * A1;
    float4* pp = reinterpret_cast<float4*>(out + wid * 65536 + (ln * 128 + s) * 8);
    pp[0] = make_float4(tmp[0], tmp[1], tmp[2], tmp[3]);
    pp[1] = make_float4(tmp[4], tmp[5], tmp[6], tmp[7]);
  }
}

// ---------------------------------------------------------------------------
// scores: for each (s,i): att[j,l] = sum_c u[c]*tq[j,c]*ta[l,c]; softmax over
// the 4096 contiguous (j,l) values (flat reshape groups by (s,i) exactly);
// write fp32 at flat element 262144 + s*262144 + i*4096 + j*64 + l.
// Block = 256 threads handles one s and 4 consecutive i (2048 blocks).
// Thread t: j in {t>>3, (t>>3)+32}, l in [(t&7)*8, +8) -> 16 values per i.
// ---------------------------------------------------------------------------
__global__ __launch_bounds__(256) void scores_kernel(
    const float* __restrict__ vp, const float* __restrict__ qp,
    const float* __restrict__ ap, float* __restrict__ out) {
  const int b = blockIdx.x;
  const int s = b >> 4;
  const int i0 = (b & 15) * 4;
  const int t = threadIdx.x;
  __shared__ float tqL[512];
  __shared__ float taL[512];
  __shared__ float uL[32];       // [ii][c]
  __shared__ float redM[4][4];
  __shared__ float redS[4][4];
  {
    const float* qr = qp + s * 512;
    const float* ar = ap + s * 512;
    tqL[t] = qr[t]; tqL[t + 256] = qr[t + 256];
    taL[t] = ar[t]; taL[t + 256] = ar[t + 256];
    if (t < 32) {
      int ii = t >> 3, c = t & 7;
      uL[t] = vp[s * 512 + c * 64 + i0 + ii] * INV_SCALE;
    }
  }
  __syncthreads();
  const int j0 = t >> 3;         // 0..31
  const int l0 = (t & 7) * 8;    // 0..56
  float acc[4][16];
#pragma unroll
  for (int ii = 0; ii < 4; ++ii)
#pragma unroll
    for (int x = 0; x < 16; ++x) acc[ii][x] = 0.f;
#pragma unroll
  for (int c = 0; c < 8; ++c) {
    float t0 = tqL[c * 64 + j0];        // broadcast reads
    float t1 = tqL[c * 64 + j0 + 32];
    float4 A0 = *reinterpret_cast<const float4*>(&taL[c * 64 + l0]);
    float4 A1v = *reinterpret_cast<const float4*>(&taL[c * 64 + l0 + 4]);
    float ta8[8] = {A0.x, A0.y, A0.z, A0.w, A1v.x, A1v.y, A1v.z, A1v.w};
#pragma unroll
    for (int ii = 0; ii < 4; ++ii) {
      float uv = uL[ii * 8 + c];
      float m0 = uv * t0;
      float m1 = uv * t1;
#pragma unroll
      for (int x = 0; x < 8; ++x) {
        acc[ii][x] = fmaf(m0, ta8[x], acc[ii][x]);
        acc[ii][8 + x] = fmaf(m1, ta8[x], acc[ii][8 + x]);
      }
    }
  }
  const int wid = t >> 6, ln = t & 63;
#pragma unroll
  for (int ii = 0; ii < 4; ++ii) {
    float m = acc[ii][0];
#pragma unroll
    for (int x = 1; x < 16; ++x) m = fmaxf(m, acc[ii][x]);
#pragma unroll
    for (int o = 32; o; o >>= 1) m = fmaxf(m, __shfl_xor(m, o));
    if (ln == 0) redM[ii][wid] = m;
  }
  __syncthreads();
#pragma unroll
  for (int ii = 0; ii < 4; ++ii) {
    float mf = fmaxf(fmaxf(redM[ii][0], redM[ii][1]),
                     fmaxf(redM[ii][2], redM[ii][3]));
    float sl = 0.f;
#pragma unroll
    for (int x = 0; x < 16; ++x) {
      float e = __expf(acc[ii][x] - mf);
      acc[ii][x] = e;
      sl += e;
    }
#pragma unroll
    for (int o = 32; o; o >>= 1) sl += __shfl_xor(sl, o);
    if (ln == 0) redS[ii][wid] = sl;
  }
  __syncthreads();
  const long sbase = 262144L + (long)s * 262144 + (long)i0 * 4096;
#pragma unroll
  for (int ii = 0; ii < 4; ++ii) {
    float tot = (redS[ii][0] + redS[ii][1]) + (redS[ii][2] + redS[ii][3]);
    float sc = 1.0f / tot;
#pragma unroll
    for (int jj = 0; jj < 2; ++jj) {
      // wave-contiguous 16B stores: element offset = 8 floats per thread slot
      float4* pp = reinterpret_cast<float4*>(
          out + sbase + ii * 4096 + (j0 + jj * 32) * 64 + l0);
      pp[0] = make_float4(acc[ii][jj * 8 + 0] * sc, acc[ii][jj * 8 + 1] * sc,
                          acc[ii][jj * 8 + 2] * sc, acc[ii][jj * 8 + 3] * sc);
      pp[1] = make_float4(acc[ii][jj * 8 + 4] * sc, acc[ii][jj * 8 + 5] * sc,
                          acc[ii][jj * 8 + 6] * sc, acc[ii][jj * 8 + 7] * sc);
    }
  }
}

extern "C" void kernel_launch(void* const* d_in, const int* in_sizes, int n_in,
                              void* d_out, int out_size, void* d_ws, size_t ws_size,
                              hipStream_t stream) {
  // setup_inputs order: v,q,a,k, 4 masks (unused), then Wv,bv,Wq,bq,Wa,ba,Wk,bk,
  //                     Wvo,bvo,Wqo,bqo,Wao,bao,Wko,bko
  int wb = 8;
  if (n_in >= 5 && in_sizes[4] == 262144) wb = 4;  // defensive: masks absent
  const float* W[8];
  const float* B[8];
  for (int i = 0; i < 8; ++i) {
    W[i] = (const float*)d_in[wb + 2 * i];
    B[i] = (const float*)d_in[wb + 2 * i + 1];
  }
  float* ws = (float*)d_ws;
  float* vp = ws;
  float* qp = ws + 65536;
  float* ap = ws + 131072;
  float* kp = ws + 196608;
  float* vo = ws + 262144;
  float* qo = ws + 327680;
  float* ao = ws + 393216;
  float* ko = ws + 458752;
  float* out = (float*)d_out;

  // Stage 1: input projections (vp = v@Wv^T+bv, etc.)
  Proj4Args a1;
  for (int i = 0; i < 4; ++i) {
    a1.x[i] = (const float*)d_in[i];
    a1.w[i] = W[i];
    a1.b[i] = B[i];
  }
  a1.y[0] = vp; a1.y[1] = qp; a1.y[2] = ap; a1.y[3] = kp;
  hipLaunchKernelGGL(proj4_kernel, dim3(256), dim3(256), 0, stream, a1);

  // Stage 2: output projections (vo = vp@Wvo^T+bvo, etc.)
  Proj4Args a2;
  a2.x[0] = vp; a2.x[1] = qp; a2.x[2] = ap; a2.x[3] = kp;
  for (int i = 0; i < 4; ++i) {
    a2.w[i] = W[4 + i];
    a2.b[i] = B[4 + i];
  }
  a2.y[0] = vo; a2.y[1] = qo; a2.y[2] = ao; a2.y[3] = ko;
  hipLaunchKernelGGL(proj4_kernel, dim3(256), dim3(256), 0, stream, a2);

  hipLaunchKernelGGL(post_kernel, dim3(128), dim3(256), 0, stream,
                     vp, qp, kp, vo, qo, ao, ko, out);
  hipLaunchKernelGGL(scores_kernel, dim3(2048), dim3(256), 0, stream,
                     vp, qp, ap, out);
}

// Round 4
// 245.200 us; speedup vs baseline: 1.1021x; 1.1021x over previous
//
#include <hip/hip_runtime.h>
#include <hip/hip_bf16.h>

// Problem constants: S=128, D=512, H=8, W=64, NUM=16, SCALE=sqrt(8)
// All inputs and outputs are fp32 (reference dtypes). fp32 compute throughout.
#define INV_SCALE 0.35355339059327373f

// ---------------------------------------------------------------------------
// Fused 4-matrix projection GEMM. y[p] = x[p] @ W[p]^T + b[p]  (torch Linear)
// x: (128,512) fp32; W: (512,512) fp32 row-major [d][k]; y fp32.
// Block = (p, 8-d tile): 256 blocks = 4 p * 64 tiles. 256 threads.
// Thread t: s = t&127, h = t>>7; computes y[s][dbase + h*4 .. +3].
// W tile (8 rows) is a contiguous 16KB global span -> coalesced LDS stage.
// x streamed in 32-k chunks, stored k-major XT[k][s] (pad 129) with register
// prefetch of the next chunk to hide global latency across chunk barriers.
// ---------------------------------------------------------------------------
struct Proj4Args {
  const float* x[4];
  const float* w[4];
  const float* b[4];
  float* y[4];
};

__global__ __launch_bounds__(256) void proj4_kernel(Proj4Args A) {
  const int blk = blockIdx.x;
  const int p = blk >> 6;
  const int dbase = (blk & 63) * 8;
  const int t = threadIdx.x;
  const int s = t & 127;
  const int h = t >> 7;  // 0/1 -> d = dbase + h*4 + di
  __shared__ float WL[8 * 512];   // [dl][k]  16 KB
  __shared__ float XT[32][129];   // [k_local][s] padded  16.5 KB
  // Stage the 8 W rows (contiguous 16KB): 1024 float4 by 256 threads.
  {
    const float4* wg = (const float4*)(A.w[p] + dbase * 512);
    float4* wl4 = (float4*)WL;
#pragma unroll
    for (int r = 0; r < 4; ++r) wl4[t + r * 256] = wg[t + r * 256];
  }
  const float* xg = A.x[p];
  const int row = t >> 3;   // + r*32 covers s-rows 0..127
  const int col = t & 7;    // float4 column within the 32-k chunk
  float acc[4] = {0.f, 0.f, 0.f, 0.f};
  float4 pre[4];
#pragma unroll
  for (int r = 0; r < 4; ++r)
    pre[r] = ((const float4*)(xg + (row + r * 32) * 512))[col];  // chunk 0
  for (int c = 0; c < 16; ++c) {
    __syncthreads();
#pragma unroll
    for (int r = 0; r < 4; ++r) {
      float4 f = pre[r];
      int rr = row + r * 32;
      XT[col * 4 + 0][rr] = f.x;
      XT[col * 4 + 1][rr] = f.y;
      XT[col * 4 + 2][rr] = f.z;
      XT[col * 4 + 3][rr] = f.w;
    }
    __syncthreads();
    if (c + 1 < 16) {
#pragma unroll
      for (int r = 0; r < 4; ++r)
        pre[r] = ((const float4*)(xg + (row + r * 32) * 512))[(c + 1) * 8 + col];
    }
#pragma unroll
    for (int k4 = 0; k4 < 8; ++k4) {
      float xv0 = XT[k4 * 4 + 0][s];
      float xv1 = XT[k4 * 4 + 1][s];
      float xv2 = XT[k4 * 4 + 2][s];
      float xv3 = XT[k4 * 4 + 3][s];
#pragma unroll
      for (int di = 0; di < 4; ++di) {
        // wave-uniform address -> LDS broadcast read (free)
        const float4 wv =
            *(const float4*)&WL[(h * 4 + di) * 512 + c * 32 + k4 * 4];
        acc[di] = fmaf(wv.x, xv0, acc[di]);
        acc[di] = fmaf(wv.y, xv1, acc[di]);
        acc[di] = fmaf(wv.z, xv2, acc[di]);
        acc[di] = fmaf(wv.w, xv3, acc[di]);
      }
    }
  }
  const float* bp = A.b[p];
  float4 o;
  o.x = acc[0] + bp[dbase + h * 4 + 0];
  o.y = acc[1] + bp[dbase + h * 4 + 1];
  o.z = acc[2] + bp[dbase + h * 4 + 2];
  o.w = acc[3] + bp[dbase + h * 4 + 3];
  *(float4*)(A.y[p] + s * 512 + dbase + h * 4) = o;
}

// ---------------------------------------------------------------------------
// Row-sum factorization + v_res/q_res/a_res/k_res (flat out elems 0..262143).
//   Sum_{j,l} att1[s,i,j,l] = (1/SCALE) sum_c tv[s,i,c]*Sq[s,c]*Sk[s,c], etc.
//   with S*[s,c] = sum over the contiguous 64-chunk c of the projected row.
//   v_res flat [i,s,c] = i*1024+s*8+c; k_res flat [s, w*8+h] at offset 196608.
// Block per s (128 blocks); waves: 0->v_res, 1->q_res, 2->a_res, 3->k_res.
// ---------------------------------------------------------------------------
__global__ __launch_bounds__(256) void post_kernel(
    const float* __restrict__ vp, const float* __restrict__ qp,
    const float* __restrict__ kp, const float* __restrict__ vo,
    const float* __restrict__ qo, const float* __restrict__ ao,
    const float* __restrict__ ko, float* __restrict__ out) {
  const int s = blockIdx.x;
  const int t = threadIdx.x;
  const int wid = t >> 6;
  const int ln = t & 63;
  __shared__ float Ssum[3][8];  // [v,q,k][c]
  const float* srcs[3] = {vp, qp, kp};
#pragma unroll
  for (int tt = 0; tt < 3; ++tt) {
    const float* r = srcs[tt] + s * 512;
    float a = r[wid * 64 + ln];          // chunk c = wid
    float b = r[256 + wid * 64 + ln];    // chunk c = wid+4
#pragma unroll
    for (int o = 32; o; o >>= 1) {
      a += __shfl_xor(a, o);
      b += __shfl_xor(b, o);
    }
    if (ln == 0) { Ssum[tt][wid] = a; Ssum[tt][wid + 4] = b; }
  }
  __syncthreads();
  if (wid == 3) {
    // k_res[s, w*8+h] = ko[s, h*64+w], w=ln
    float tmp[8];
#pragma unroll
    for (int h = 0; h < 8; ++h)
      tmp[h] = ko[s * 512 + h * 64 + ln];
    float4* pp = reinterpret_cast<float4*>(out + 196608 + (s * 64 + ln) * 8);
    pp[0] = make_float4(tmp[0], tmp[1], tmp[2], tmp[3]);
    pp[1] = make_float4(tmp[4], tmp[5], tmp[6], tmp[7]);
  } else {
    // wave0 (v_res): tv=vp, factors Sq*Sk; wave1 (q_res): tq=qp, Sv*Sk;
    // wave2 (a_res): tk=kp, Sv*Sq.
    const float* base = (wid == 0) ? vp : (wid == 1) ? qp : kp;
    const float* obase = (wid == 0) ? vo : (wid == 1) ? qo : ao;
    const int c0 = (wid == 0) ? 1 : 0;
    const int c1 = (wid == 2) ? 1 : 2;
    float A1 = 0.f;
#pragma unroll
    for (int c = 0; c < 8; ++c)
      A1 += base[s * 512 + c * 64 + ln] * (Ssum[c0][c] * Ssum[c1][c]);
    A1 *= INV_SCALE;
    float tmp[8];
#pragma unroll
    for (int c = 0; c < 8; ++c)
      tmp[c] = obase[s * 512 + c * 64 + ln] * A1;
    float4* pp = reinterpret_cast<float4*>(out + wid * 65536 + (ln * 128 + s) * 8);
    pp[0] = make_float4(tmp[0], tmp[1], tmp[2], tmp[3]);
    pp[1] = make_float4(tmp[4], tmp[5], tmp[6], tmp[7]);
  }
}

// ---------------------------------------------------------------------------
// scores: for each (s,i): att[j,l] = sum_c u[c]*tq[j,c]*ta[l,c]; softmax over
// the 4096 contiguous (j,l) values (flat reshape groups by (s,i) exactly);
// write fp32 at flat element 262144 + s*262144 + i*4096 + j*64 + l.
// Block = 256 threads handles one s and 4 consecutive i (2048 blocks).
// Thread t: j in {t>>3, (t>>3)+32}, l in [(t&7)*8, +8) -> 16 values per i.
// ---------------------------------------------------------------------------
__global__ __launch_bounds__(256) void scores_kernel(
    const float* __restrict__ vp, const float* __restrict__ qp,
    const float* __restrict__ ap, float* __restrict__ out) {
  const int b = blockIdx.x;
  const int s = b >> 4;
  const int i0 = (b & 15) * 4;
  const int t = threadIdx.x;
  __shared__ float tqL[512];
  __shared__ float taL[512];
  __shared__ float uL[32];       // [ii][c]
  __shared__ float redM[4][4];
  __shared__ float redS[4][4];
  {
    const float* qr = qp + s * 512;
    const float* ar = ap + s * 512;
    tqL[t] = qr[t]; tqL[t + 256] = qr[t + 256];
    taL[t] = ar[t]; taL[t + 256] = ar[t + 256];
    if (t < 32) {
      int ii = t >> 3, c = t & 7;
      uL[t] = vp[s * 512 + c * 64 + i0 + ii] * INV_SCALE;
    }
  }
  __syncthreads();
  const int j0 = t >> 3;         // 0..31
  const int l0 = (t & 7) * 8;    // 0..56
  float acc[4][16];
#pragma unroll
  for (int ii = 0; ii < 4; ++ii)
#pragma unroll
    for (int x = 0; x < 16; ++x) acc[ii][x] = 0.f;
#pragma unroll
  for (int c = 0; c < 8; ++c) {
    float t0 = tqL[c * 64 + j0];        // broadcast reads
    float t1 = tqL[c * 64 + j0 + 32];
    float4 A0 = *reinterpret_cast<const float4*>(&taL[c * 64 + l0]);
    float4 A1v = *reinterpret_cast<const float4*>(&taL[c * 64 + l0 + 4]);
    float ta8[8] = {A0.x, A0.y, A0.z, A0.w, A1v.x, A1v.y, A1v.z, A1v.w};
#pragma unroll
    for (int ii = 0; ii < 4; ++ii) {
      float uv = uL[ii * 8 + c];
      float m0 = uv * t0;
      float m1 = uv * t1;
#pragma unroll
      for (int x = 0; x < 8; ++x) {
        acc[ii][x] = fmaf(m0, ta8[x], acc[ii][x]);
        acc[ii][8 + x] = fmaf(m1, ta8[x], acc[ii][8 + x]);
      }
    }
  }
  const int wid = t >> 6, ln = t & 63;
#pragma unroll
  for (int ii = 0; ii < 4; ++ii) {
    float m = acc[ii][0];
#pragma unroll
    for (int x = 1; x < 16; ++x) m = fmaxf(m, acc[ii][x]);
#pragma unroll
    for (int o = 32; o; o >>= 1) m = fmaxf(m, __shfl_xor(m, o));
    if (ln == 0) redM[ii][wid] = m;
  }
  __syncthreads();
#pragma unroll
  for (int ii = 0; ii < 4; ++ii) {
    float mf = fmaxf(fmaxf(redM[ii][0], redM[ii][1]),
                     fmaxf(redM[ii][2], redM[ii][3]));
    float sl = 0.f;
#pragma unroll
    for (int x = 0; x < 16; ++x) {
      float e = __expf(acc[ii][x] - mf);
      acc[ii][x] = e;
      sl += e;
    }
#pragma unroll
    for (int o = 32; o; o >>= 1) sl += __shfl_xor(sl, o);
    if (ln == 0) redS[ii][wid] = sl;
  }
  __syncthreads();
  const long sbase = 262144L + (long)s * 262144 + (long)i0 * 4096;
#pragma unroll
  for (int ii = 0; ii < 4; ++ii) {
    float tot = (redS[ii][0] + redS[ii][1]) + (redS[ii][2] + redS[ii][3]);
    float sc = 1.0f / tot;
#pragma unroll
    for (int jj = 0; jj < 2; ++jj) {
      // wave-contiguous 16B stores
      float4* pp = reinterpret_cast<float4*>(
          out + sbase + ii * 4096 + (j0 + jj * 32) * 64 + l0);
      pp[0] = make_float4(acc[ii][jj * 8 + 0] * sc, acc[ii][jj * 8 + 1] * sc,
                          acc[ii][jj * 8 + 2] * sc, acc[ii][jj * 8 + 3] * sc);
      pp[1] = make_float4(acc[ii][jj * 8 + 4] * sc, acc[ii][jj * 8 + 5] * sc,
                          acc[ii][jj * 8 + 6] * sc, acc[ii][jj * 8 + 7] * sc);
    }
  }
}

extern "C" void kernel_launch(void* const* d_in, const int* in_sizes, int n_in,
                              void* d_out, int out_size, void* d_ws, size_t ws_size,
                              hipStream_t stream) {
  // setup_inputs order: v,q,a,k, 4 masks (unused), then Wv,bv,Wq,bq,Wa,ba,Wk,bk,
  //                     Wvo,bvo,Wqo,bqo,Wao,bao,Wko,bko
  int wb = 8;
  if (n_in >= 5 && in_sizes[4] == 262144) wb = 4;  // defensive: masks absent
  const float* W[8];
  const float* B[8];
  for (int i = 0; i < 8; ++i) {
    W[i] = (const float*)d_in[wb + 2 * i];
    B[i] = (const float*)d_in[wb + 2 * i + 1];
  }
  float* ws = (float*)d_ws;
  float* vp = ws;
  float* qp = ws + 65536;
  float* ap = ws + 131072;
  float* kp = ws + 196608;
  float* vo = ws + 262144;
  float* qo = ws + 327680;
  float* ao = ws + 393216;
  float* ko = ws + 458752;
  float* out = (float*)d_out;

  // Stage 1: input projections (vp = v@Wv^T+bv, etc.)
  Proj4Args a1;
  for (int i = 0; i < 4; ++i) {
    a1.x[i] = (const float*)d_in[i];
    a1.w[i] = W[i];
    a1.b[i] = B[i];
  }
  a1.y[0] = vp; a1.y[1] = qp; a1.y[2] = ap; a1.y[3] = kp;
  hipLaunchKernelGGL(proj4_kernel, dim3(256), dim3(256), 0, stream, a1);

  // Stage 2: output projections (vo = vp@Wvo^T+bvo, etc.)
  Proj4Args a2;
  a2.x[0] = vp; a2.x[1] = qp; a2.x[2] = ap; a2.x[3] = kp;
  for (int i = 0; i < 4; ++i) {
    a2.w[i] = W[4 + i];
    a2.b[i] = B[4 + i];
  }
  a2.y[0] = vo; a2.y[1] = qo; a2.y[2] = ao; a2.y[3] = ko;
  hipLaunchKernelGGL(proj4_kernel, dim3(256), dim3(256), 0, stream, a2);

  hipLaunchKernelGGL(post_kernel, dim3(128), dim3(256), 0, stream,
                     vp, qp, kp, vo, qo, ao, ko, out);
  hipLaunchKernelGGL(scores_kernel, dim3(2048), dim3(256), 0, stream,
                     vp, qp, ap, out);
}

// Round 5
// 240.088 us; speedup vs baseline: 1.1256x; 1.0213x over previous
//
#include <hip/hip_runtime.h>
#include <hip/hip_bf16.h>

// Problem constants: S=128, D=512, H=8, W=64, NUM=16, SCALE=sqrt(8)
// All inputs and outputs are fp32 (reference dtypes). fp32 compute throughout.
#define INV_SCALE 0.35355339059327373f

struct Proj4Args {
  const float* x[4];
  const float* w[4];
  const float* b[4];
  float* y[4];
};

// ---------------------------------------------------------------------------
// Projection GEMM body. y[p] = x[p] @ W[p]^T + b[p]  (torch Linear)
// x: (128,512) fp32; W: (512,512) fp32 row-major [d][k]; y fp32.
// blk = (p, 8-d tile): 256 block-tasks = 4 p * 64 tiles. 256 threads.
// Thread t: s = t&127, h = t>>7; computes y[s][dbase + h*4 .. +3].
// W tile (8 rows) is a contiguous 16KB global span -> coalesced LDS stage.
// x streamed in 32-k chunks, stored k-major XT[k][s] (pad 129) with register
// prefetch of the next chunk to hide global latency across chunk barriers.
// LDS use: WL 16 KB + XT 16.5 KB (carved from SH).
// ---------------------------------------------------------------------------
__device__ __forceinline__ void proj_body(const Proj4Args& A, int blk, int t,
                                          float* SH) {
  const int p = blk >> 6;
  const int dbase = (blk & 63) * 8;
  const int s = t & 127;
  const int h = t >> 7;  // 0/1 -> d = dbase + h*4 + di
  float* WL = SH;                              // [dl][k]  8*512
  float(*XT)[129] = (float(*)[129])(SH + 4096);  // [k_local][s] padded
  {
    const float4* wg = (const float4*)(A.w[p] + dbase * 512);
    float4* wl4 = (float4*)WL;
#pragma unroll
    for (int r = 0; r < 4; ++r) wl4[t + r * 256] = wg[t + r * 256];
  }
  const float* xg = A.x[p];
  const int row = t >> 3;   // + r*32 covers s-rows 0..127
  const int col = t & 7;    // float4 column within the 32-k chunk
  float acc[4] = {0.f, 0.f, 0.f, 0.f};
  float4 pre[4];
#pragma unroll
  for (int r = 0; r < 4; ++r)
    pre[r] = ((const float4*)(xg + (row + r * 32) * 512))[col];  // chunk 0
  for (int c = 0; c < 16; ++c) {
    __syncthreads();
#pragma unroll
    for (int r = 0; r < 4; ++r) {
      float4 f = pre[r];
      int rr = row + r * 32;
      XT[col * 4 + 0][rr] = f.x;
      XT[col * 4 + 1][rr] = f.y;
      XT[col * 4 + 2][rr] = f.z;
      XT[col * 4 + 3][rr] = f.w;
    }
    __syncthreads();
    if (c + 1 < 16) {
#pragma unroll
      for (int r = 0; r < 4; ++r)
        pre[r] = ((const float4*)(xg + (row + r * 32) * 512))[(c + 1) * 8 + col];
    }
#pragma unroll
    for (int k4 = 0; k4 < 8; ++k4) {
      float xv0 = XT[k4 * 4 + 0][s];
      float xv1 = XT[k4 * 4 + 1][s];
      float xv2 = XT[k4 * 4 + 2][s];
      float xv3 = XT[k4 * 4 + 3][s];
#pragma unroll
      for (int di = 0; di < 4; ++di) {
        // wave-uniform address -> LDS broadcast read (free)
        const float4 wv =
            *(const float4*)&WL[(h * 4 + di) * 512 + c * 32 + k4 * 4];
        acc[di] = fmaf(wv.x, xv0, acc[di]);
        acc[di] = fmaf(wv.y, xv1, acc[di]);
        acc[di] = fmaf(wv.z, xv2, acc[di]);
        acc[di] = fmaf(wv.w, xv3, acc[di]);
      }
    }
  }
  const float* bp = A.b[p];
  float4 o;
  o.x = acc[0] + bp[dbase + h * 4 + 0];
  o.y = acc[1] + bp[dbase + h * 4 + 1];
  o.z = acc[2] + bp[dbase + h * 4 + 2];
  o.w = acc[3] + bp[dbase + h * 4 + 3];
  *(float4*)(A.y[p] + s * 512 + dbase + h * 4) = o;
}

__global__ __launch_bounds__(256) void proj4_kernel(Proj4Args A) {
  __shared__ float SH[8224];  // 4096 (WL) + 4128 (XT)
  proj_body(A, blockIdx.x, threadIdx.x, SH);
}

// ---------------------------------------------------------------------------
// scores body: for each (s,i): att[j,l] = sum_c u[c]*tq[j,c]*ta[l,c]; softmax
// over the 4096 contiguous (j,l) (flat reshape groups by (s,i) exactly);
// write fp32 at flat element 262144 + s*262144 + i*4096 + j*64 + l.
// blk (0..2047) = one s and 4 consecutive i. 256 threads.
// Thread t: j in {t>>3, (t>>3)+32}, l in [(t&7)*8, +8) -> 16 values per i.
// LDS: tqL 512, taL 512, uL 32, redM 16, redS 16 (carved from SH).
// ---------------------------------------------------------------------------
__device__ __forceinline__ void scores_body(const float* __restrict__ vp,
                                            const float* __restrict__ qp,
                                            const float* __restrict__ ap,
                                            float* __restrict__ out, int b,
                                            int t, float* SH) {
  const int s = b >> 4;
  const int i0 = (b & 15) * 4;
  float* tqL = SH;
  float* taL = SH + 512;
  float* uL = SH + 1024;                       // [ii][c]
  float(*redM)[4] = (float(*)[4])(SH + 1056);  // [ii][wid]
  float(*redS)[4] = (float(*)[4])(SH + 1072);
  {
    const float* qr = qp + s * 512;
    const float* ar = ap + s * 512;
    tqL[t] = qr[t]; tqL[t + 256] = qr[t + 256];
    taL[t] = ar[t]; taL[t + 256] = ar[t + 256];
    if (t < 32) {
      int ii = t >> 3, c = t & 7;
      uL[t] = vp[s * 512 + c * 64 + i0 + ii] * INV_SCALE;
    }
  }
  __syncthreads();
  const int j0 = t >> 3;         // 0..31
  const int l0 = (t & 7) * 8;    // 0..56
  float acc[4][16];
#pragma unroll
  for (int ii = 0; ii < 4; ++ii)
#pragma unroll
    for (int x = 0; x < 16; ++x) acc[ii][x] = 0.f;
#pragma unroll
  for (int c = 0; c < 8; ++c) {
    float t0 = tqL[c * 64 + j0];        // broadcast reads
    float t1 = tqL[c * 64 + j0 + 32];
    float4 A0 = *reinterpret_cast<const float4*>(&taL[c * 64 + l0]);
    float4 A1v = *reinterpret_cast<const float4*>(&taL[c * 64 + l0 + 4]);
    float ta8[8] = {A0.x, A0.y, A0.z, A0.w, A1v.x, A1v.y, A1v.z, A1v.w};
#pragma unroll
    for (int ii = 0; ii < 4; ++ii) {
      float uv = uL[ii * 8 + c];
      float m0 = uv * t0;
      float m1 = uv * t1;
#pragma unroll
      for (int x = 0; x < 8; ++x) {
        acc[ii][x] = fmaf(m0, ta8[x], acc[ii][x]);
        acc[ii][8 + x] = fmaf(m1, ta8[x], acc[ii][8 + x]);
      }
    }
  }
  const int wid = t >> 6, ln = t & 63;
#pragma unroll
  for (int ii = 0; ii < 4; ++ii) {
    float m = acc[ii][0];
#pragma unroll
    for (int x = 1; x < 16; ++x) m = fmaxf(m, acc[ii][x]);
#pragma unroll
    for (int o = 32; o; o >>= 1) m = fmaxf(m, __shfl_xor(m, o));
    if (ln == 0) redM[ii][wid] = m;
  }
  __syncthreads();
#pragma unroll
  for (int ii = 0; ii < 4; ++ii) {
    float mf = fmaxf(fmaxf(redM[ii][0], redM[ii][1]),
                     fmaxf(redM[ii][2], redM[ii][3]));
    float sl = 0.f;
#pragma unroll
    for (int x = 0; x < 16; ++x) {
      float e = __expf(acc[ii][x] - mf);
      acc[ii][x] = e;
      sl += e;
    }
#pragma unroll
    for (int o = 32; o; o >>= 1) sl += __shfl_xor(sl, o);
    if (ln == 0) redS[ii][wid] = sl;
  }
  __syncthreads();
  const long sbase = 262144L + (long)s * 262144 + (long)i0 * 4096;
#pragma unroll
  for (int ii = 0; ii < 4; ++ii) {
    float tot = (redS[ii][0] + redS[ii][1]) + (redS[ii][2] + redS[ii][3]);
    float sc = 1.0f / tot;
#pragma unroll
    for (int jj = 0; jj < 2; ++jj) {
      // wave-contiguous 16B stores
      float4* pp = reinterpret_cast<float4*>(
          out + sbase + ii * 4096 + (j0 + jj * 32) * 64 + l0);
      pp[0] = make_float4(acc[ii][jj * 8 + 0] * sc, acc[ii][jj * 8 + 1] * sc,
                          acc[ii][jj * 8 + 2] * sc, acc[ii][jj * 8 + 3] * sc);
      pp[1] = make_float4(acc[ii][jj * 8 + 4] * sc, acc[ii][jj * 8 + 5] * sc,
                          acc[ii][jj * 8 + 6] * sc, acc[ii][jj * 8 + 7] * sc);
    }
  }
}

// ---------------------------------------------------------------------------
// Fused launch: blocks 0..2047 -> scores (needs stage-1 only);
//               blocks 2048..2303 -> proj stage 2 (independent of scores).
// Static LDS = proj requirement (32.9 KB) -> 4 blocks/CU; scores is
// write-bound so 16 waves/CU still saturates the store stream.
// ---------------------------------------------------------------------------
struct FusedArgs {
  Proj4Args pj;      // stage-2 projections
  const float* vp;
  const float* qp;
  const float* ap;
  float* out;
};

__global__ __launch_bounds__(256) void fused_kernel(FusedArgs F) {
  __shared__ float SH[8224];
  const int b = blockIdx.x;
  if (b < 2048)
    scores_body(F.vp, F.qp, F.ap, F.out, b, threadIdx.x, SH);
  else
    proj_body(F.pj, b - 2048, threadIdx.x, SH);
}

// ---------------------------------------------------------------------------
// Row-sum factorization + v_res/q_res/a_res/k_res (flat out elems 0..262143).
//   Sum_{j,l} att1[s,i,j,l] = (1/SCALE) sum_c tv[s,i,c]*Sq[s,c]*Sk[s,c], etc.
//   with S*[s,c] = sum over the contiguous 64-chunk c of the projected row.
//   v_res flat [i,s,c] = i*1024+s*8+c; k_res flat [s, w*8+h] at offset 196608.
// Block per s (128 blocks); waves: 0->v_res, 1->q_res, 2->a_res, 3->k_res.
// ---------------------------------------------------------------------------
__global__ __launch_bounds__(256) void post_kernel(
    const float* __restrict__ vp, const float* __restrict__ qp,
    const float* __restrict__ kp, const float* __restrict__ vo,
    const float* __restrict__ qo, const float* __restrict__ ao,
    const float* __restrict__ ko, float* __restrict__ out) {
  const int s = blockIdx.x;
  const int t = threadIdx.x;
  const int wid = t >> 6;
  const int ln = t & 63;
  __shared__ float Ssum[3][8];  // [v,q,k][c]
  const float* srcs[3] = {vp, qp, kp};
#pragma unroll
  for (int tt = 0; tt < 3; ++tt) {
    const float* r = srcs[tt] + s * 512;
    float a = r[wid * 64 + ln];          // chunk c = wid
    float b = r[256 + wid * 64 + ln];    // chunk c = wid+4
#pragma unroll
    for (int o = 32; o; o >>= 1) {
      a += __shfl_xor(a, o);
      b += __shfl_xor(b, o);
    }
    if (ln == 0) { Ssum[tt][wid] = a; Ssum[tt][wid + 4] = b; }
  }
  __syncthreads();
  if (wid == 3) {
    // k_res[s, w*8+h] = ko[s, h*64+w], w=ln
    float tmp[8];
#pragma unroll
    for (int h = 0; h < 8; ++h)
      tmp[h] = ko[s * 512 + h * 64 + ln];
    float4* pp = reinterpret_cast<float4*>(out + 196608 + (s * 64 + ln) * 8);
    pp[0] = make_float4(tmp[0], tmp[1], tmp[2], tmp[3]);
    pp[1] = make_float4(tmp[4], tmp[5], tmp[6], tmp[7]);
  } else {
    // wave0 (v_res): tv=vp, factors Sq*Sk; wave1 (q_res): tq=qp, Sv*Sk;
    // wave2 (a_res): tk=kp, Sv*Sq.
    const float* base = (wid == 0) ? vp : (wid == 1) ? qp : kp;
    const float* obase = (wid == 0) ? vo : (wid == 1) ? qo : ao;
    const int c0 = (wid == 0) ? 1 : 0;
    const int c1 = (wid == 2) ? 1 : 2;
    float A1 = 0.f;
#pragma unroll
    for (int c = 0; c < 8; ++c)
      A1 += base[s * 512 + c * 64 + ln] * (Ssum[c0][c] * Ssum[c1][c]);
    A1 *= INV_SCALE;
    float tmp[8];
#pragma unroll
    for (int c = 0; c < 8; ++c)
      tmp[c] = obase[s * 512 + c * 64 + ln] * A1;
    float4* pp = reinterpret_cast<float4*>(out + wid * 65536 + (ln * 128 + s) * 8);
    pp[0] = make_float4(tmp[0], tmp[1], tmp[2], tmp[3]);
    pp[1] = make_float4(tmp[4], tmp[5], tmp[6], tmp[7]);
  }
}

extern "C" void kernel_launch(void* const* d_in, const int* in_sizes, int n_in,
                              void* d_out, int out_size, void* d_ws, size_t ws_size,
                              hipStream_t stream) {
  // setup_inputs order: v,q,a,k, 4 masks (unused), then Wv,bv,Wq,bq,Wa,ba,Wk,bk,
  //                     Wvo,bvo,Wqo,bqo,Wao,bao,Wko,bko
  int wb = 8;
  if (n_in >= 5 && in_sizes[4] == 262144) wb = 4;  // defensive: masks absent
  const float* W[8];
  const float* B[8];
  for (int i = 0; i < 8; ++i) {
    W[i] = (const float*)d_in[wb + 2 * i];
    B[i] = (const float*)d_in[wb + 2 * i + 1];
  }
  float* ws = (float*)d_ws;
  float* vp = ws;
  float* qp = ws + 65536;
  float* ap = ws + 131072;
  float* kp = ws + 196608;
  float* vo = ws + 262144;
  float* qo = ws + 327680;
  float* ao = ws + 393216;
  float* ko = ws + 458752;
  float* out = (float*)d_out;

  // Stage 1: input projections (vp = v@Wv^T+bv, etc.)
  Proj4Args a1;
  for (int i = 0; i < 4; ++i) {
    a1.x[i] = (const float*)d_in[i];
    a1.w[i] = W[i];
    a1.b[i] = B[i];
  }
  a1.y[0] = vp; a1.y[1] = qp; a1.y[2] = ap; a1.y[3] = kp;
  hipLaunchKernelGGL(proj4_kernel, dim3(256), dim3(256), 0, stream, a1);

  // Fused: scores (2048 blocks) + stage-2 projections (256 blocks)
  FusedArgs F;
  F.pj.x[0] = vp; F.pj.x[1] = qp; F.pj.x[2] = ap; F.pj.x[3] = kp;
  for (int i = 0; i < 4; ++i) {
    F.pj.w[i] = W[4 + i];
    F.pj.b[i] = B[4 + i];
  }
  F.pj.y[0] = vo; F.pj.y[1] = qo; F.pj.y[2] = ao; F.pj.y[3] = ko;
  F.vp = vp; F.qp = qp; F.ap = ap; F.out = out;
  hipLaunchKernelGGL(fused_kernel, dim3(2304), dim3(256), 0, stream, F);

  hipLaunchKernelGGL(post_kernel, dim3(128), dim3(256), 0, stream,
                     vp, qp, kp, vo, qo, ao, ko, out);
}

// Round 6
// 233.033 us; speedup vs baseline: 1.1597x; 1.0303x over previous
//
#include <hip/hip_runtime.h>
#include <hip/hip_bf16.h>

// Problem constants: S=128, D=512, H=8, W=64, NUM=16, SCALE=sqrt(8)
// All inputs and outputs are fp32 (reference dtypes). fp32 compute throughout.
#define INV_SCALE 0.35355339059327373f

struct Proj4Args {
  const float* x[4];
  const float* w[4];
  const float* b[4];
  float* y[4];
};

// ---------------------------------------------------------------------------
// Stage-1 projection GEMM. y[p] = x[p] @ W[p]^T + b[p]  (torch Linear)
// x: (128,512) fp32; W: (512,512) fp32 row-major [d][k]; y fp32.
// blk = (p, 8-d tile): 256 blocks = 4 p * 64 tiles. 256 threads.
// Thread t: s = t&127, h = t>>7; computes y[s][dbase + h*4 .. +3].
// W tile (8 rows) = contiguous 16KB span -> coalesced LDS stage; x streamed
// in 32-k chunks k-major XT[k][129] with register prefetch of chunk c+1.
// ---------------------------------------------------------------------------
__device__ __forceinline__ void gemm8_body(const float* xg, const float* wg_p,
                                           const float* bp, int dbase, int t,
                                           float* SH, float o[4]) {
  const int s = t & 127;
  const int h = t >> 7;
  float* WL = SH;                                // [dl][k]  8*512
  float(*XT)[129] = (float(*)[129])(SH + 4096);  // [k_local][s] padded
  {
    const float4* wg = (const float4*)(wg_p + dbase * 512);
    float4* wl4 = (float4*)WL;
#pragma unroll
    for (int r = 0; r < 4; ++r) wl4[t + r * 256] = wg[t + r * 256];
  }
  const int row = t >> 3;   // + r*32 covers s-rows 0..127
  const int col = t & 7;    // float4 column within the 32-k chunk
  float acc[4] = {0.f, 0.f, 0.f, 0.f};
  float4 pre[4];
#pragma unroll
  for (int r = 0; r < 4; ++r)
    pre[r] = ((const float4*)(xg + (row + r * 32) * 512))[col];  // chunk 0
  for (int c = 0; c < 16; ++c) {
    __syncthreads();
#pragma unroll
    for (int r = 0; r < 4; ++r) {
      float4 f = pre[r];
      int rr = row + r * 32;
      XT[col * 4 + 0][rr] = f.x;
      XT[col * 4 + 1][rr] = f.y;
      XT[col * 4 + 2][rr] = f.z;
      XT[col * 4 + 3][rr] = f.w;
    }
    __syncthreads();
    if (c + 1 < 16) {
#pragma unroll
      for (int r = 0; r < 4; ++r)
        pre[r] = ((const float4*)(xg + (row + r * 32) * 512))[(c + 1) * 8 + col];
    }
#pragma unroll
    for (int k4 = 0; k4 < 8; ++k4) {
      float xv0 = XT[k4 * 4 + 0][s];
      float xv1 = XT[k4 * 4 + 1][s];
      float xv2 = XT[k4 * 4 + 2][s];
      float xv3 = XT[k4 * 4 + 3][s];
#pragma unroll
      for (int di = 0; di < 4; ++di) {
        // wave-uniform address -> LDS broadcast read (free)
        const float4 wv =
            *(const float4*)&WL[(h * 4 + di) * 512 + c * 32 + k4 * 4];
        acc[di] = fmaf(wv.x, xv0, acc[di]);
        acc[di] = fmaf(wv.y, xv1, acc[di]);
        acc[di] = fmaf(wv.z, xv2, acc[di]);
        acc[di] = fmaf(wv.w, xv3, acc[di]);
      }
    }
  }
#pragma unroll
  for (int di = 0; di < 4; ++di) o[di] = acc[di] + bp[dbase + h * 4 + di];
}

__global__ __launch_bounds__(256) void proj4_kernel(Proj4Args A) {
  __shared__ float SH[8224];  // 4096 (WL) + 4128 (XT)
  const int blk = blockIdx.x;
  const int p = blk >> 6;
  const int dbase = (blk & 63) * 8;
  const int t = threadIdx.x;
  float o[4];
  gemm8_body(A.x[p], A.w[p], A.b[p], dbase, t, SH, o);
  const int s = t & 127;
  const int h = t >> 7;
  *(float4*)(A.y[p] + s * 512 + dbase + h * 4) = make_float4(o[0], o[1], o[2], o[3]);
}

// ---------------------------------------------------------------------------
// Fused second launch.
//   blocks 0..255      -> stage-2 projection + DIRECT final-output epilogue
//   blocks 256..2303   -> scores (softmax att), needs stage-1 only
// proj2 blocks lead so their longer body overlaps the write-bound scores
// stream instead of extending its tail.
// ---------------------------------------------------------------------------
struct FusedArgs {
  const float* w2[4];  // Wvo,Wqo,Wao,Wko
  const float* b2[4];
  const float* vp;
  const float* qp;
  const float* ap;
  const float* kp;
  float* out;
};

// Stage-2 direct epilogue:
//   p=0: v_res[i,s,c]=vo[s,c*64+i]*A1v[s,i], A1v=INV_SCALE*sum_c vp*Sq*Sk
//   p=1: q_res (qo, A1q from qp,Sv,Sk);  p=2: a_res (ao, A1a from kp,Sv,Sq)
//   p=3: k_res[s, w*8+h] = ko[s, h*64+w]  (pure transpose)
// Chunk sums S*[s,c]=sum_{64-chunk c} recomputed per block (L2-hot, no races).
__device__ __forceinline__ void proj2_direct_body(const FusedArgs& F, int blk,
                                                  int t, float* SH) {
  const int p = blk >> 6;
  const int dbase = (blk & 63) * 8;
  const float* xsrc[4] = {F.vp, F.qp, F.ap, F.kp};
  float o[4];
  gemm8_body(xsrc[p], F.w2[p], F.b2[p], dbase, t, SH, o);
  const int s = t & 127;
  const int h = t >> 7;
  const int c_head = dbase >> 6;   // head index of this d-tile
  const int i0 = (dbase & 63) + h * 4;  // within-head coordinate base
  if (p == 3) {
    // k_res at flat offset 196608: [s, w*8 + head]
#pragma unroll
    for (int di = 0; di < 4; ++di)
      F.out[196608 + s * 512 + (i0 + di) * 8 + c_head] = o[di];
    return;  // p is block-uniform: no divergent-barrier hazard
  }
  const float* fac = (p == 0) ? F.vp : (p == 1) ? F.qp : F.kp;
  const float* S0 = (p == 0) ? F.qp : F.vp;
  const float* S1 = (p == 2) ? F.qp : F.kp;
  __syncthreads();  // all GEMM LDS reads done; reuse SH
  float* Sm = SH;   // [2][128][8]
#pragma unroll
  for (int m = 0; m < 2; ++m) {
    const float* M = m ? S1 : S0;
#pragma unroll
    for (int cc = 0; cc < 4; ++cc) {
      const int c = h * 4 + cc;
      const float4* r4 = (const float4*)(M + s * 512 + c * 64);
      float sum = 0.f;
#pragma unroll
      for (int u = 0; u < 16; ++u) {
        float4 f = r4[u];
        sum += (f.x + f.y) + (f.z + f.w);
      }
      Sm[m * 1024 + s * 8 + c] = sum;
    }
  }
  __syncthreads();
  float prod[8];
#pragma unroll
  for (int c = 0; c < 8; ++c)
    prod[c] = Sm[s * 8 + c] * Sm[1024 + s * 8 + c];
#pragma unroll
  for (int di = 0; di < 4; ++di) {
    const int i = i0 + di;
    float A1 = 0.f;
#pragma unroll
    for (int c = 0; c < 8; ++c)
      A1 = fmaf(fac[s * 512 + c * 64 + i], prod[c], A1);
    // {v,q,a}_res at flat offset p*65536: [i, s*8 + head]
    F.out[p * 65536 + i * 1024 + s * 8 + c_head] = o[di] * (A1 * INV_SCALE);
  }
}

// scores body: for each (s,i): att[j,l] = sum_c u[c]*tq[j,c]*ta[l,c]; softmax
// over the 4096 contiguous (j,l) (flat reshape groups exactly by (s,i));
// write fp32 at flat element 262144 + s*262144 + i*4096 + j*64 + l.
// blk = one s and 4 consecutive i. Thread t: j in {t>>3,(t>>3)+32},
// l in [(t&7)*8,+8) -> 16 values per i.
__device__ __forceinline__ void scores_body(const float* __restrict__ vp,
                                            const float* __restrict__ qp,
                                            const float* __restrict__ ap,
                                            float* __restrict__ out, int b,
                                            int t, float* SH) {
  const int s = b >> 4;
  const int i0 = (b & 15) * 4;
  float* tqL = SH;
  float* taL = SH + 512;
  float* uL = SH + 1024;                       // [ii][c]
  float(*redM)[4] = (float(*)[4])(SH + 1056);  // [ii][wid]
  float(*redS)[4] = (float(*)[4])(SH + 1072);
  {
    const float* qr = qp + s * 512;
    const float* ar = ap + s * 512;
    tqL[t] = qr[t]; tqL[t + 256] = qr[t + 256];
    taL[t] = ar[t]; taL[t + 256] = ar[t + 256];
    if (t < 32) {
      int ii = t >> 3, c = t & 7;
      uL[t] = vp[s * 512 + c * 64 + i0 + ii] * INV_SCALE;
    }
  }
  __syncthreads();
  const int j0 = t >> 3;         // 0..31
  const int l0 = (t & 7) * 8;    // 0..56
  float acc[4][16];
#pragma unroll
  for (int ii = 0; ii < 4; ++ii)
#pragma unroll
    for (int x = 0; x < 16; ++x) acc[ii][x] = 0.f;
#pragma unroll
  for (int c = 0; c < 8; ++c) {
    float t0 = tqL[c * 64 + j0];        // broadcast reads
    float t1 = tqL[c * 64 + j0 + 32];
    float4 A0 = *reinterpret_cast<const float4*>(&taL[c * 64 + l0]);
    float4 A1v = *reinterpret_cast<const float4*>(&taL[c * 64 + l0 + 4]);
    float ta8[8] = {A0.x, A0.y, A0.z, A0.w, A1v.x, A1v.y, A1v.z, A1v.w};
#pragma unroll
    for (int ii = 0; ii < 4; ++ii) {
      float uv = uL[ii * 8 + c];
      float m0 = uv * t0;
      float m1 = uv * t1;
#pragma unroll
      for (int x = 0; x < 8; ++x) {
        acc[ii][x] = fmaf(m0, ta8[x], acc[ii][x]);
        acc[ii][8 + x] = fmaf(m1, ta8[x], acc[ii][8 + x]);
      }
    }
  }
  const int wid = t >> 6, ln = t & 63;
#pragma unroll
  for (int ii = 0; ii < 4; ++ii) {
    float m = acc[ii][0];
#pragma unroll
    for (int x = 1; x < 16; ++x) m = fmaxf(m, acc[ii][x]);
#pragma unroll
    for (int o = 32; o; o >>= 1) m = fmaxf(m, __shfl_xor(m, o));
    if (ln == 0) redM[ii][wid] = m;
  }
  __syncthreads();
#pragma unroll
  for (int ii = 0; ii < 4; ++ii) {
    float mf = fmaxf(fmaxf(redM[ii][0], redM[ii][1]),
                     fmaxf(redM[ii][2], redM[ii][3]));
    float sl = 0.f;
#pragma unroll
    for (int x = 0; x < 16; ++x) {
      float e = __expf(acc[ii][x] - mf);
      acc[ii][x] = e;
      sl += e;
    }
#pragma unroll
    for (int o = 32; o; o >>= 1) sl += __shfl_xor(sl, o);
    if (ln == 0) redS[ii][wid] = sl;
  }
  __syncthreads();
  const long sbase = 262144L + (long)s * 262144 + (long)i0 * 4096;
#pragma unroll
  for (int ii = 0; ii < 4; ++ii) {
    float tot = (redS[ii][0] + redS[ii][1]) + (redS[ii][2] + redS[ii][3]);
    float sc = 1.0f / tot;
#pragma unroll
    for (int jj = 0; jj < 2; ++jj) {
      // wave-contiguous 16B stores
      float4* pp = reinterpret_cast<float4*>(
          out + sbase + ii * 4096 + (j0 + jj * 32) * 64 + l0);
      pp[0] = make_float4(acc[ii][jj * 8 + 0] * sc, acc[ii][jj * 8 + 1] * sc,
                          acc[ii][jj * 8 + 2] * sc, acc[ii][jj * 8 + 3] * sc);
      pp[1] = make_float4(acc[ii][jj * 8 + 4] * sc, acc[ii][jj * 8 + 5] * sc,
                          acc[ii][jj * 8 + 6] * sc, acc[ii][jj * 8 + 7] * sc);
    }
  }
}

__global__ __launch_bounds__(256) void fused_kernel(FusedArgs F) {
  __shared__ float SH[8224];
  const int b = blockIdx.x;
  if (b < 256)
    proj2_direct_body(F, b, threadIdx.x, SH);
  else
    scores_body(F.vp, F.qp, F.ap, F.out, b - 256, threadIdx.x, SH);
}

extern "C" void kernel_launch(void* const* d_in, const int* in_sizes, int n_in,
                              void* d_out, int out_size, void* d_ws, size_t ws_size,
                              hipStream_t stream) {
  // setup_inputs order: v,q,a,k, 4 masks (unused), then Wv,bv,Wq,bq,Wa,ba,Wk,bk,
  //                     Wvo,bvo,Wqo,bqo,Wao,bao,Wko,bko
  int wb = 8;
  if (n_in >= 5 && in_sizes[4] == 262144) wb = 4;  // defensive: masks absent
  const float* W[8];
  const float* B[8];
  for (int i = 0; i < 8; ++i) {
    W[i] = (const float*)d_in[wb + 2 * i];
    B[i] = (const float*)d_in[wb + 2 * i + 1];
  }
  float* ws = (float*)d_ws;
  float* vp = ws;
  float* qp = ws + 65536;
  float* ap = ws + 131072;
  float* kp = ws + 196608;
  float* out = (float*)d_out;

  // Stage 1: input projections (vp = v@Wv^T+bv, etc.)
  Proj4Args a1;
  for (int i = 0; i < 4; ++i) {
    a1.x[i] = (const float*)d_in[i];
    a1.w[i] = W[i];
    a1.b[i] = B[i];
  }
  a1.y[0] = vp; a1.y[1] = qp; a1.y[2] = ap; a1.y[3] = kp;
  hipLaunchKernelGGL(proj4_kernel, dim3(256), dim3(256), 0, stream, a1);

  // Fused: stage-2 projections w/ direct final outputs (256) + scores (2048)
  FusedArgs F;
  for (int i = 0; i < 4; ++i) {
    F.w2[i] = W[4 + i];
    F.b2[i] = B[4 + i];
  }
  F.vp = vp; F.qp = qp; F.ap = ap; F.kp = kp; F.out = out;
  hipLaunchKernelGGL(fused_kernel, dim3(2304), dim3(256), 0, stream, F);
}